// Round 3
// baseline (295.153 us; speedup 1.0000x reference)
//
#include <hip/hip_runtime.h>

typedef unsigned short u16;
typedef unsigned int   u32;
typedef __bf16 bfv8 __attribute__((ext_vector_type(8)));   // MFMA A/B frag: 8 bf16
typedef float  f32x4 __attribute__((ext_vector_type(4)));  // MFMA C/D frag
typedef short  s16x4 __attribute__((ext_vector_type(4)));  // 16x16x16 bf16_1k frag

#define B_   2
#define T_   2048
#define D_   1024
#define H_   16
#define HKV_ 4
#define NQK  1280            // qkv buffer holds Q(1024) + K(256); V goes to vT
#define BT_  (B_*T_)
// q_gain fold also includes 1/sqrt(64)=0.125 and log2(e) (softmax in log2 domain)
#define QSCALE 0.18033688011112042f
#define L2_10K 0.41524101186092515f   // log2(10000)/32
#define I2PI   0.15915494309189535f   // 1/(2*pi) — HW trig input is revolutions

__device__ __forceinline__ u16 f2bf(float f) {   // native RNE cvt
  __bf16 h = (__bf16)f; u16 s; __builtin_memcpy(&s, &h, 2); return s;
}

// async global->LDS, 16B per lane; LDS dst = wave-uniform base + lane*16 (m104)
__device__ __forceinline__ void load16(const u16* g, u16* l) {
  auto gp = (const __attribute__((address_space(1))) u32*)(uintptr_t)g;
  auto lp = (__attribute__((address_space(3))) u32*)(uintptr_t)l;
  __builtin_amdgcn_global_load_lds(gp, lp, 16, 0, 0);
}

// HW trig: v_sin_f32/v_cos_f32 take revolutions; explicit fract reduction
__device__ __forceinline__ void hw_sincos_rev(float rev, float& s, float& c) {
  rev -= floorf(rev);                  // folds to v_fract_f32
  s = __builtin_amdgcn_sinf(rev);
  c = __builtin_amdgcn_cosf(rev);
}

// ---------------- fp32 -> bf16 convert: x AND all weights in ONE launch ----------
// dst is contiguous: xb(4194304) | Wq(1048576) | Wk(262144) | Wv(262144) | Wp(1048576)
__global__ void conv_all_kernel(const float* __restrict__ x,
                                const float* __restrict__ wq, const float* __restrict__ wk,
                                const float* __restrict__ wv, const float* __restrict__ wp,
                                u16* __restrict__ dst) {
  int i = (blockIdx.x * 256 + threadIdx.x) * 4;
  const float* s; int off;
  if (i < 4194304) { s = x; off = i; }
  else {
    int j = i - 4194304;
    if      (j < 1048576) { s = wq; off = j; }
    else if (j < 1310720) { s = wk; off = j - 1048576; }
    else if (j < 1572864) { s = wv; off = j - 1310720; }
    else                  { s = wp; off = j - 1572864; }
  }
  float4 v = *(const float4*)(s + off);
  ushort4 o; o.x = f2bf(v.x); o.y = f2bf(v.y); o.z = f2bf(v.z); o.w = f2bf(v.w);
  *(ushort4*)(dst + i) = o;
}

// ---------------- bf16 GEMM, C = A(M,K) @ B(N,K)^T ----------------
// R1 version (best measured tie, 157.57). R0-R2 post-mortem: GEMM structure
// (128x64/2w, 128x128/4w, 64x128/2w+counted-vmcnt) measured IDENTICAL within
// 0.1us — GEMM is not the mover at this size. Frozen at R1's 128x128 4-wave,
// one barrier per K-step, double-buffered LDS.
// MODE 0: f32 out ld=N.
// MODE 2: fused QKV epilogue — each WAVE's 64-col strip = exactly one head.
//         Q/K heads get RoPE (+q_gain*QSCALE on Q) on fp32 accumulators;
//         V heads scattered transposed to vT[b][kvh][d][t].
template<int MODE>
__global__ __launch_bounds__(256) void gemm_bt(const u16* __restrict__ A,
                                               const u16* __restrict__ Bm,
                                               void* __restrict__ C,
                                               u16* __restrict__ vT,
                                               const float* __restrict__ qg,
                                               int M, int N, int K) {
  __shared__ __align__(16) u16 As[2][128 * 32];   // 16 KB
  __shared__ __align__(16) u16 Bs[2][128 * 32];   // 16 KB
  const int tid  = threadIdx.x;
  const int wave = tid >> 6, lane = tid & 63;
  const int quad = lane >> 4, l16 = lane & 15;
  const int m0 = blockIdx.y * 128, n0 = blockIdx.x * 128;
  const int wm = (wave >> 1) * 64, wn = (wave & 1) * 64;
  const int lr = lane >> 2, lc = (lane & 3) * 8;   // 4 lanes per 32-half row

  f32x4 acc[4][4];
  for (int mi = 0; mi < 4; ++mi)
    for (int ni = 0; ni < 4; ++ni) acc[mi][ni] = (f32x4){0.f, 0.f, 0.f, 0.f};

  auto stage = [&](int kk, int buf) {
    #pragma unroll
    for (int u = 0; u < 2; ++u) {            // A: 8 chunks of 16 rows
      const int c = u * 4 + wave;            // wave-uniform chunk id
      load16(A + (size_t)(m0 + c*16 + lr) * K + kk + lc, As[buf] + c * 512);
    }
    #pragma unroll
    for (int u = 0; u < 2; ++u) {            // B: 8 chunks of 16 rows
      const int c = u * 4 + wave;
      load16(Bm + (size_t)(n0 + c*16 + lr) * K + kk + lc, Bs[buf] + c * 512);
    }
  };

  const int nIter = K >> 5;                  // 32
  stage(0, 0);
  for (int it = 0; it < nIter; ++it) {
    __syncthreads();                         // implicit vmcnt(0): DMA(it) done;
                                             // also protects buf[(it+1)&1] from prev reads
    if (it + 1 < nIter) stage(((it + 1) << 5), (it + 1) & 1);   // overlaps compute(it)
    const u16* Ab = As[it & 1];
    const u16* Bb = Bs[it & 1];
    bfv8 af[4], bf_[4];
    #pragma unroll
    for (int i = 0; i < 4; ++i) af[i]  = *(const bfv8*)(Ab + (wm + i*16 + l16)*32 + 8*quad);
    #pragma unroll
    for (int i = 0; i < 4; ++i) bf_[i] = *(const bfv8*)(Bb + (wn + i*16 + l16)*32 + 8*quad);
    #pragma unroll
    for (int mi = 0; mi < 4; ++mi)
      #pragma unroll
      for (int ni = 0; ni < 4; ++ni)
        acc[mi][ni] = __builtin_amdgcn_mfma_f32_16x16x32_bf16(af[mi], bf_[ni], acc[mi][ni], 0, 0, 0);
  }

  // C/D layout: row = 4*quad + reg, col = l16 (+16*ni + n0 + wn)
  const int nc = n0 + wn;                    // wave's 64-wide column strip base
  if (MODE == 0) {
    #pragma unroll
    for (int mi = 0; mi < 4; ++mi)
      #pragma unroll
      for (int ni = 0; ni < 4; ++ni)
        #pragma unroll
        for (int r = 0; r < 4; ++r)
          ((float*)C)[(size_t)(m0 + wm + mi*16 + 4*quad + r) * N + nc + ni*16 + l16]
            = acc[mi][ni][r];
  } else {
    if (nc < NQK) {                          // Q or K head: apply RoPE here
      const bool isQ = nc < 1024;
      const float gain = isQ ? qg[nc >> 6] * QSCALE : 1.0f;
      // lane's head-internal cols: j0=l16 (ni 0/2 pair), j1=l16+16 (ni 1/3 pair)
      const float inv0 = exp2f(-(float)l16 * L2_10K) * I2PI;          // rev/step
      const float inv1 = exp2f(-(float)(l16 + 16) * L2_10K) * I2PI;
      #pragma unroll
      for (int mi = 0; mi < 4; ++mi) {
        const int rowg = m0 + wm + mi*16 + 4*quad;
        u16* dst = (u16*)C + (size_t)rowg * NQK + nc + l16;
        #pragma unroll
        for (int r = 0; r < 4; ++r) {
          const int t = (rowg + r) & (T_ - 1);
          float s0, c0, s1, c1;
          hw_sincos_rev((float)t * inv0, s0, c0);
          hw_sincos_rev((float)t * inv1, s1, c1);
          const float x1a = acc[mi][0][r], x2a = acc[mi][2][r];
          const float x1b = acc[mi][1][r], x2b = acc[mi][3][r];
          u16* drow = dst + (size_t)r * NQK;
          drow[0]  = f2bf((x1a*c0 - x2a*s0) * gain);
          drow[16] = f2bf((x1b*c1 - x2b*s1) * gain);
          drow[32] = f2bf((x1a*s0 + x2a*c0) * gain);
          drow[48] = f2bf((x1b*s1 + x2b*c1) * gain);
        }
      }
    } else {              // V head -> transposed vT[b][kvh][d][t]
      const int kvh = (nc - NQK) >> 6;
      #pragma unroll
      for (int mi = 0; mi < 4; ++mi)
        #pragma unroll
        for (int ni = 0; ni < 4; ++ni) {
          const int d = ni*16 + l16;
          const int rowg = m0 + wm + mi*16 + 4*quad;
          const int bb = rowg >> 11, t = rowg & (T_ - 1);
          ushort4 w4;
          w4.x = f2bf(acc[mi][ni][0]); w4.y = f2bf(acc[mi][ni][1]);
          w4.z = f2bf(acc[mi][ni][2]); w4.w = f2bf(acc[mi][ni][3]);
          *(ushort4*)(vT + ((size_t)((bb*HKV_ + kvh)*64 + d)) * T_ + t) = w4;
        }
    }
  }
}

// ---------------- Flash attention (causal, GQA, paired q-tiles, S^T trick) ----------------
// R13: BARRIER-FREE. K/V fragments read DIRECTLY from global (L1/L2-served) —
// no LDS staging, no __syncthreads, no vmcnt drains (Common-mistake #7 /
// m165-m169: staging L2-fitting data is pure overhead; K+V per (b,kvh) is
// 512 KB, all 8 sets = 4 MB << L2; one 64x64 K-tile + V-tile = 16 KB, L1-fit,
// shared by 4 waves x 64 blocks per kvh). Waves run fully decoupled; a
// tile-step's 24 loads issue up-front and hide under the QK^T MFMA chain.
// Un-swizzled direct addressing (staging permutation was an involution):
//   K frag:  k0 = K[row][8q..], k1 = K[row][8q+32..]   (row = s0+ni*16+l16)
//   V frag:  va = V^T[d][s0+16*ni+4*quad..]            (d   = dt*16+l16)
// Paired q-tiles (i, 31-i): uniform 33 strip-tiles/block, K/V frag reads
// shared across both strips. St = K Q^T feeds P directly into PV
// (O^T = V^T P^T) as 16x16x16bf16_1k B-frags — no P round-trip.
// Fixed-max softmax (M=0, log2 domain, scores O(1)-bounded).
template<bool DOA, bool DIAGA, bool DIAGB>
__device__ __forceinline__ void attn_tile(const u16* __restrict__ Kg,
                                          const u16* __restrict__ Vg,
                                          int l16, int quad,
                                          const bfv8* qA, const bfv8* qB,
                                          float& psA, float& psB,
                                          f32x4 oA[4], f32x4 oB[4],
                                          int qColA, int qColB, int s0) {
  // issue ALL tile loads up-front (24 per lane): K 8x16B + V 16x8B
  bfv8 k0[4], k1[4];
  s16x4 va[4][4];
  #pragma unroll
  for (int ni = 0; ni < 4; ++ni) {
    const u16* Krow = Kg + (size_t)(s0 + ni*16 + l16) * NQK + 8*quad;
    k0[ni] = *(const bfv8*)(Krow);
    k1[ni] = *(const bfv8*)(Krow + 32);
  }
  #pragma unroll
  for (int dt = 0; dt < 4; ++dt) {
    const u16* Vrow = Vg + (size_t)(dt*16 + l16) * T_ + s0 + 4*quad;
    #pragma unroll
    for (int ni = 0; ni < 4; ++ni)
      va[dt][ni] = *(const s16x4*)(Vrow + 16*ni);
  }
  f32x4 stA[4], stB[4];
  #pragma unroll
  for (int ni = 0; ni < 4; ++ni) {
    if (DOA) {
      stA[ni] = __builtin_amdgcn_mfma_f32_16x16x32_bf16(k0[ni], qA[0], (f32x4){0.f,0.f,0.f,0.f}, 0, 0, 0);
      stA[ni] = __builtin_amdgcn_mfma_f32_16x16x32_bf16(k1[ni], qA[1], stA[ni], 0, 0, 0);
    }
    stB[ni] = __builtin_amdgcn_mfma_f32_16x16x32_bf16(k0[ni], qB[0], (f32x4){0.f,0.f,0.f,0.f}, 0, 0, 0);
    stB[ni] = __builtin_amdgcn_mfma_f32_16x16x32_bf16(k1[ni], qB[1], stB[ni], 0, 0, 0);
  }
  // mask + exp2 + per-lane row-sum + pack to bf16 B-frags (P^T in registers)
  s16x4 pbA[4], pbB[4];
  #pragma unroll
  for (int ni = 0; ni < 4; ++ni)
    #pragma unroll
    for (int r = 0; r < 4; ++r) {
      const int key = s0 + ni*16 + 4*quad + r;
      if (DOA) {
        float v = stA[ni][r];
        if (DIAGA) v = (key <= qColA) ? v : -3.0e38f;
        const float p = __builtin_amdgcn_exp2f(v);
        psA += p;
        pbA[ni][r] = (short)f2bf(p);
      }
      float v = stB[ni][r];
      if (DIAGB) v = (key <= qColB) ? v : -3.0e38f;
      const float p = __builtin_amdgcn_exp2f(v);
      psB += p;
      pbB[ni][r] = (short)f2bf(p);
    }
  // O^T += V^T P^T  (shared V frags)
  #pragma unroll
  for (int ni = 0; ni < 4; ++ni)
    #pragma unroll
    for (int dt = 0; dt < 4; ++dt) {
      if (DOA) oA[dt] = __builtin_amdgcn_mfma_f32_16x16x16bf16_1k(va[dt][ni], pbA[ni], oA[dt], 0, 0, 0);
      oB[dt] = __builtin_amdgcn_mfma_f32_16x16x16bf16_1k(va[dt][ni], pbB[ni], oB[dt], 0, 0, 0);
    }
}

__global__ __launch_bounds__(256) void attn_kernel(const u16* __restrict__ qkv,
                                                   const u16* __restrict__ vT,
                                                   u16* __restrict__ o) {
  const int pr = blockIdx.x;            // pair id 0..15 -> q-tiles (pr, 31-pr)
  const int h  = blockIdx.y;
  const int b  = blockIdx.z;
  const int kvh = h >> 2;
  const int tid = threadIdx.x;
  const int wave = tid >> 6, lane = tid & 63;
  const int quad = lane >> 4, l16 = lane & 15;

  const int qtA = pr, qtB = 31 - pr;
  const int nk  = qtB + 1;              // qtA < qtB always (pr in 0..15)

  const u16* qAp = qkv + (size_t)(b*T_ + qtA*64 + wave*16 + l16) * NQK + h*64 + 8*quad;
  const u16* qBp = qkv + (size_t)(b*T_ + qtB*64 + wave*16 + l16) * NQK + h*64 + 8*quad;
  const bfv8 qA[2] = { *(const bfv8*)qAp, *(const bfv8*)(qAp + 32) };
  const bfv8 qB[2] = { *(const bfv8*)qBp, *(const bfv8*)(qBp + 32) };

  float psA = 0.f, psB = 0.f;
  f32x4 oA[4], oB[4];
  #pragma unroll
  for (int d = 0; d < 4; ++d) oA[d] = oB[d] = (f32x4){0.f, 0.f, 0.f, 0.f};

  const u16* Kg = qkv + (size_t)(b*T_) * NQK + 1024 + kvh*64;
  const u16* Vg = vT  + (size_t)((b*HKV_ + kvh) * 64) * T_;

  const int qColA = qtA*64 + wave*16 + l16;    // lane's q row (strip A)
  const int qColB = qtB*64 + wave*16 + l16;

  // Phase 1: kt in [0, qtA) — both strips, no diag
  for (int kt = 0; kt < qtA; ++kt)
    attn_tile<true, false, false>(Kg, Vg, l16, quad, qA, qB,
                                  psA, psB, oA, oB, qColA, qColB, kt*64);
  // kt = qtA — both strips, diag on A (qtA < nk-1 always)
  attn_tile<true, true, false>(Kg, Vg, l16, quad, qA, qB,
                               psA, psB, oA, oB, qColA, qColB, qtA*64);
  // Phase 2: kt in (qtA, nk-1) — strip B only
  for (int kt = qtA + 1; kt < nk - 1; ++kt)
    attn_tile<false, false, false>(Kg, Vg, l16, quad, qA, qB,
                                   psA, psB, oA, oB, qColA, qColB, kt*64);
  // kt = nk-1 — strip B, diag
  attn_tile<false, false, true>(Kg, Vg, l16, quad, qA, qB,
                                psA, psB, oA, oB, qColA, qColB, (nk-1)*64);

  // row sums: partials live on the 4 quads of each q-row lane
  #pragma unroll
  for (int off = 16; off < 64; off <<= 1) {
    psA += __shfl_xor(psA, off);
    psB += __shfl_xor(psB, off);
  }
  const float ivA = 1.0f / psA, ivB = 1.0f / psB;

  // O^T C-layout: col=l16=qrow, row=4*quad+r = d (+16*dt) -> pack 4 d's per store
  #pragma unroll
  for (int dt = 0; dt < 4; ++dt) {
    ushort4 wA, wB;
    wA.x = f2bf(oA[dt][0]*ivA); wA.y = f2bf(oA[dt][1]*ivA);
    wA.z = f2bf(oA[dt][2]*ivA); wA.w = f2bf(oA[dt][3]*ivA);
    wB.x = f2bf(oB[dt][0]*ivB); wB.y = f2bf(oB[dt][1]*ivB);
    wB.z = f2bf(oB[dt][2]*ivB); wB.w = f2bf(oB[dt][3]*ivB);
    *(ushort4*)(o + (size_t)(b*T_ + qColA) * D_ + h*64 + dt*16 + 4*quad) = wA;
    *(ushort4*)(o + (size_t)(b*T_ + qColB) * D_ + h*64 + dt*16 + 4*quad) = wB;
  }
}

// ---------------- launch ----------------
extern "C" void kernel_launch(void* const* d_in, const int* in_sizes, int n_in,
                              void* d_out, int out_size, void* d_ws, size_t ws_size,
                              hipStream_t stream) {
  const float* x  = (const float*)d_in[0];
  const float* Wq = (const float*)d_in[1];
  const float* Wk = (const float*)d_in[2];
  const float* Wv = (const float*)d_in[3];
  const float* Wp = (const float*)d_in[4];
  const float* qg = (const float*)d_in[5];

  u16* xb   = (u16*)d_ws;                        // 4096 x 1024 (reused as ob)
  u16* wqkv = xb   + (size_t)BT_ * D_;           // 1536 x 1024
  u16* wpb  = wqkv + (size_t)1536 * D_;          // 1024 x 1024 (contiguous after wqkv)
  u16* qkvb = wpb  + (size_t)D_ * D_;            // 4096 x 1280 (Q|K)
  u16* vT   = qkvb + (size_t)BT_ * NQK;          // [2][4][64][2048]
  u16* ob   = xb;

  conv_all_kernel<<<dim3((4194304 + 2621440) / 1024), dim3(256), 0, stream>>>(
      x, Wq, Wk, Wv, Wp, xb);

  gemm_bt<2><<<dim3(12, 32), dim3(256), 0, stream>>>(xb, wqkv, qkvb, vT, qg, BT_, 1536, D_);
  attn_kernel<<<dim3(16, H_, B_), dim3(256), 0, stream>>>(qkvb, vT, ob);
  gemm_bt<0><<<dim3(8, 32), dim3(256), 0, stream>>>(ob, wpb, d_out, (u16*)nullptr, nullptr, BT_, D_, D_);
}

// Round 4
// 156.414 us; speedup vs baseline: 1.8870x; 1.8870x over previous
//
#include <hip/hip_runtime.h>

typedef unsigned short u16;
typedef unsigned int   u32;
typedef __bf16 bfv8 __attribute__((ext_vector_type(8)));   // MFMA A/B frag: 8 bf16
typedef float  f32x4 __attribute__((ext_vector_type(4)));  // MFMA C/D frag
typedef short  s16x4 __attribute__((ext_vector_type(4)));  // 16x16x16 bf16_1k frag

#define B_   2
#define T_   2048
#define D_   1024
#define H_   16
#define HKV_ 4
#define NQK  1280            // qkv buffer holds Q(1024) + K(256); V goes to vT
#define BT_  (B_*T_)
// q_gain fold also includes 1/sqrt(64)=0.125 and log2(e) (softmax in log2 domain)
#define QSCALE 0.18033688011112042f
#define L2_10K 0.41524101186092515f   // log2(10000)/32
#define I2PI   0.15915494309189535f   // 1/(2*pi) — HW trig input is revolutions

__device__ __forceinline__ u16 f2bf(float f) {   // native RNE cvt
  __bf16 h = (__bf16)f; u16 s; __builtin_memcpy(&s, &h, 2); return s;
}

// async global->LDS, 16B per lane; LDS dst = wave-uniform base + lane*16 (m104)
__device__ __forceinline__ void load16(const u16* g, u16* l) {
  auto gp = (const __attribute__((address_space(1))) u32*)(uintptr_t)g;
  auto lp = (__attribute__((address_space(3))) u32*)(uintptr_t)l;
  __builtin_amdgcn_global_load_lds(gp, lp, 16, 0, 0);
}

// HW trig: v_sin_f32/v_cos_f32 take revolutions; explicit fract reduction
__device__ __forceinline__ void hw_sincos_rev(float rev, float& s, float& c) {
  rev -= floorf(rev);                  // folds to v_fract_f32
  s = __builtin_amdgcn_sinf(rev);
  c = __builtin_amdgcn_cosf(rev);
}

// ---------------- fp32 -> bf16 convert: x AND all weights in ONE launch ----------
// dst is contiguous: xb(4194304) | Wq(1048576) | Wk(262144) | Wv(262144) | Wp(1048576)
__global__ void conv_all_kernel(const float* __restrict__ x,
                                const float* __restrict__ wq, const float* __restrict__ wk,
                                const float* __restrict__ wv, const float* __restrict__ wp,
                                u16* __restrict__ dst) {
  int i = (blockIdx.x * 256 + threadIdx.x) * 4;
  const float* s; int off;
  if (i < 4194304) { s = x; off = i; }
  else {
    int j = i - 4194304;
    if      (j < 1048576) { s = wq; off = j; }
    else if (j < 1310720) { s = wk; off = j - 1048576; }
    else if (j < 1572864) { s = wv; off = j - 1310720; }
    else                  { s = wp; off = j - 1572864; }
  }
  float4 v = *(const float4*)(s + off);
  ushort4 o; o.x = f2bf(v.x); o.y = f2bf(v.y); o.z = f2bf(v.z); o.w = f2bf(v.w);
  *(ushort4*)(dst + i) = o;
}

// ---------------- bf16 GEMM, C = A(M,K) @ B(N,K)^T ----------------
// R1 structure (best measured tie, 157.57) + R14: T1 XCD-chunked blockIdx
// swizzle. Rationale: consecutive linear block ids round-robin across the 8
// XCDs; x-fastest ids put the 12 blocks sharing one 256KB A row-panel on
// different XCDs -> each panel HBM-fetched ~8x. Remap lid=(orig%8)*(nwg/8)
// +orig/8 (bijective; nwg=384/256 both %8==0) gives each XCD a contiguous
// chunk = 4 complete row panels -> A fetched once per panel.
// GEMM inner structure frozen (R0-R2: three tile/pipeline variants identical).
// MODE 0: f32 out ld=N.  MODE 2: fused QKV epilogue (RoPE on Q/K, V->vT).
template<int MODE>
__global__ __launch_bounds__(256) void gemm_bt(const u16* __restrict__ A,
                                               const u16* __restrict__ Bm,
                                               void* __restrict__ C,
                                               u16* __restrict__ vT,
                                               const float* __restrict__ qg,
                                               int M, int N, int K) {
  __shared__ __align__(16) u16 As[2][128 * 32];   // 16 KB
  __shared__ __align__(16) u16 Bs[2][128 * 32];   // 16 KB
  const int tid  = threadIdx.x;
  const int wave = tid >> 6, lane = tid & 63;
  const int quad = lane >> 4, l16 = lane & 15;
  // T1 XCD swizzle (compile-time gx: QKV grid x=12, proj grid x=8)
  const int gx   = (MODE == 2) ? 12 : 8;
  const int nwg  = gx * 32;
  const int orig = blockIdx.x + gx * blockIdx.y;
  const int lid  = (orig & 7) * (nwg >> 3) + (orig >> 3);
  const int m0 = (lid / gx) * 128, n0 = (lid % gx) * 128;
  const int wm = (wave >> 1) * 64, wn = (wave & 1) * 64;
  const int lr = lane >> 2, lc = (lane & 3) * 8;   // 4 lanes per 32-half row

  f32x4 acc[4][4];
  for (int mi = 0; mi < 4; ++mi)
    for (int ni = 0; ni < 4; ++ni) acc[mi][ni] = (f32x4){0.f, 0.f, 0.f, 0.f};

  auto stage = [&](int kk, int buf) {
    #pragma unroll
    for (int u = 0; u < 2; ++u) {            // A: 8 chunks of 16 rows
      const int c = u * 4 + wave;            // wave-uniform chunk id
      load16(A + (size_t)(m0 + c*16 + lr) * K + kk + lc, As[buf] + c * 512);
    }
    #pragma unroll
    for (int u = 0; u < 2; ++u) {            // B: 8 chunks of 16 rows
      const int c = u * 4 + wave;
      load16(Bm + (size_t)(n0 + c*16 + lr) * K + kk + lc, Bs[buf] + c * 512);
    }
  };

  const int nIter = K >> 5;                  // 32
  stage(0, 0);
  for (int it = 0; it < nIter; ++it) {
    __syncthreads();                         // implicit vmcnt(0): DMA(it) done;
                                             // also protects buf[(it+1)&1] from prev reads
    if (it + 1 < nIter) stage(((it + 1) << 5), (it + 1) & 1);   // overlaps compute(it)
    const u16* Ab = As[it & 1];
    const u16* Bb = Bs[it & 1];
    bfv8 af[4], bf_[4];
    #pragma unroll
    for (int i = 0; i < 4; ++i) af[i]  = *(const bfv8*)(Ab + (wm + i*16 + l16)*32 + 8*quad);
    #pragma unroll
    for (int i = 0; i < 4; ++i) bf_[i] = *(const bfv8*)(Bb + (wn + i*16 + l16)*32 + 8*quad);
    #pragma unroll
    for (int mi = 0; mi < 4; ++mi)
      #pragma unroll
      for (int ni = 0; ni < 4; ++ni)
        acc[mi][ni] = __builtin_amdgcn_mfma_f32_16x16x32_bf16(af[mi], bf_[ni], acc[mi][ni], 0, 0, 0);
  }

  // C/D layout: row = 4*quad + reg, col = l16 (+16*ni + n0 + wn)
  const int nc = n0 + wn;                    // wave's 64-wide column strip base
  if (MODE == 0) {
    #pragma unroll
    for (int mi = 0; mi < 4; ++mi)
      #pragma unroll
      for (int ni = 0; ni < 4; ++ni)
        #pragma unroll
        for (int r = 0; r < 4; ++r)
          ((float*)C)[(size_t)(m0 + wm + mi*16 + 4*quad + r) * N + nc + ni*16 + l16]
            = acc[mi][ni][r];
  } else {
    if (nc < NQK) {                          // Q or K head: apply RoPE here
      const bool isQ = nc < 1024;
      const float gain = isQ ? qg[nc >> 6] * QSCALE : 1.0f;
      // lane's head-internal cols: j0=l16 (ni 0/2 pair), j1=l16+16 (ni 1/3 pair)
      const float inv0 = exp2f(-(float)l16 * L2_10K) * I2PI;          // rev/step
      const float inv1 = exp2f(-(float)(l16 + 16) * L2_10K) * I2PI;
      #pragma unroll
      for (int mi = 0; mi < 4; ++mi) {
        const int rowg = m0 + wm + mi*16 + 4*quad;
        u16* dst = (u16*)C + (size_t)rowg * NQK + nc + l16;
        #pragma unroll
        for (int r = 0; r < 4; ++r) {
          const int t = (rowg + r) & (T_ - 1);
          float s0, c0, s1, c1;
          hw_sincos_rev((float)t * inv0, s0, c0);
          hw_sincos_rev((float)t * inv1, s1, c1);
          const float x1a = acc[mi][0][r], x2a = acc[mi][2][r];
          const float x1b = acc[mi][1][r], x2b = acc[mi][3][r];
          u16* drow = dst + (size_t)r * NQK;
          drow[0]  = f2bf((x1a*c0 - x2a*s0) * gain);
          drow[16] = f2bf((x1b*c1 - x2b*s1) * gain);
          drow[32] = f2bf((x1a*s0 + x2a*c0) * gain);
          drow[48] = f2bf((x1b*s1 + x2b*c1) * gain);
        }
      }
    } else {              // V head -> transposed vT[b][kvh][d][t]
      const int kvh = (nc - NQK) >> 6;
      #pragma unroll
      for (int mi = 0; mi < 4; ++mi)
        #pragma unroll
        for (int ni = 0; ni < 4; ++ni) {
          const int d = ni*16 + l16;
          const int rowg = m0 + wm + mi*16 + 4*quad;
          const int bb = rowg >> 11, t = rowg & (T_ - 1);
          ushort4 w4;
          w4.x = f2bf(acc[mi][ni][0]); w4.y = f2bf(acc[mi][ni][1]);
          w4.z = f2bf(acc[mi][ni][2]); w4.w = f2bf(acc[mi][ni][3]);
          *(ushort4*)(vT + ((size_t)((bb*HKV_ + kvh)*64 + d)) * T_ + t) = w4;
        }
    }
  }
}

// ---------------- Flash attention (causal, GQA, paired q-tiles, S^T trick) ----------------
// R8 version VERBATIM (best measured: 45.6 us). R2 (counted-vmcnt, 4 buf):
// +4.5us — asm WAITBAR defeats compiler lgkmcnt scheduling. R3 (no LDS,
// direct global): +129us — latency-bound (MfmaUtil 5.9%), the 1-deep DMA
// prefetch was load-bearing. This structure is a verified local optimum.
// Paired q-tiles (i, 31-i): uniform 33 strip-tiles/block AND K/V frag reads
// shared across both strips. St = K Q^T (C-layout lane l16 = q-row, keys
// 4*quad+r) feeds P directly into PV (O^T = V^T P^T) as 16x16x16bf16_1k
// B-frags — no P LDS round-trip. Fixed-max softmax (M=0, log2 domain).
// COMPILE-TIME strip/diag specialization (R7 lesson: runtime bools get
// if-converted inside unrolled loops -> dead strip's exp2/MFMA chain executes).
template<bool DOA, bool DIAGA, bool DIAGB>
__device__ __forceinline__ void attn_tile(const u16* KB, const u16* VB,
                                          int l16, int quad,
                                          const bfv8* qA, const bfv8* qB,
                                          float& psA, float& psB,
                                          f32x4 oA[4], f32x4 oB[4],
                                          int qColA, int qColB, int s0) {
  const int sw = l16 & 7;
  f32x4 stA[4], stB[4];
  #pragma unroll
  for (int ni = 0; ni < 4; ++ni) {
    const int row = ni*16 + l16;           // key row in K tile
    bfv8 k0 = *(const bfv8*)(KB + row*64 + 8*(quad ^ sw));
    bfv8 k1 = *(const bfv8*)(KB + row*64 + 8*((quad + 4) ^ sw));
    if (DOA) {
      stA[ni] = __builtin_amdgcn_mfma_f32_16x16x32_bf16(k0, qA[0], (f32x4){0.f,0.f,0.f,0.f}, 0, 0, 0);
      stA[ni] = __builtin_amdgcn_mfma_f32_16x16x32_bf16(k1, qA[1], stA[ni], 0, 0, 0);
    }
    stB[ni] = __builtin_amdgcn_mfma_f32_16x16x32_bf16(k0, qB[0], (f32x4){0.f,0.f,0.f,0.f}, 0, 0, 0);
    stB[ni] = __builtin_amdgcn_mfma_f32_16x16x32_bf16(k1, qB[1], stB[ni], 0, 0, 0);
  }
  // mask + exp2 + per-lane row-sum + pack to bf16 B-frags (P^T in registers)
  s16x4 pbA[4], pbB[4];
  #pragma unroll
  for (int ni = 0; ni < 4; ++ni)
    #pragma unroll
    for (int r = 0; r < 4; ++r) {
      const int key = s0 + ni*16 + 4*quad + r;
      if (DOA) {
        float v = stA[ni][r];
        if (DIAGA) v = (key <= qColA) ? v : -3.0e38f;
        const float p = __builtin_amdgcn_exp2f(v);
        psA += p;
        pbA[ni][r] = (short)f2bf(p);
      }
      float v = stB[ni][r];
      if (DIAGB) v = (key <= qColB) ? v : -3.0e38f;
      const float p = __builtin_amdgcn_exp2f(v);
      psB += p;
      pbB[ni][r] = (short)f2bf(p);
    }
  // O^T += V^T P^T  (shared V frags)
  #pragma unroll
  for (int ni = 0; ni < 4; ++ni) {
    const int vofs = 8*((2*ni + (quad >> 1)) ^ sw) + 4*(quad & 1);
    #pragma unroll
    for (int dt = 0; dt < 4; ++dt) {
      s16x4 va = *(const s16x4*)(VB + (dt*16 + l16)*64 + vofs);
      if (DOA) oA[dt] = __builtin_amdgcn_mfma_f32_16x16x16bf16_1k(va, pbA[ni], oA[dt], 0, 0, 0);
      oB[dt] = __builtin_amdgcn_mfma_f32_16x16x16bf16_1k(va, pbB[ni], oB[dt], 0, 0, 0);
    }
  }
}

__global__ __launch_bounds__(256) void attn_kernel(const u16* __restrict__ qkv,
                                                   const u16* __restrict__ vT,
                                                   u16* __restrict__ o) {
  const int pr = blockIdx.x;            // pair id 0..15 -> q-tiles (pr, 31-pr)
  const int h  = blockIdx.y;
  const int b  = blockIdx.z;
  const int kvh = h >> 2;
  const int tid = threadIdx.x;
  const int wave = tid >> 6, lane = tid & 63;
  const int quad = lane >> 4, l16 = lane & 15;

  const int qtA = pr, qtB = 31 - pr;
  const int nk  = qtB + 1;              // qtA < qtB always (pr in 0..15)

  __shared__ __align__(16) u16 Kl[2][64 * 64];
  __shared__ __align__(16) u16 Vl[2][64 * 64];

  const u16* qAp = qkv + (size_t)(b*T_ + qtA*64 + wave*16 + l16) * NQK + h*64 + 8*quad;
  const u16* qBp = qkv + (size_t)(b*T_ + qtB*64 + wave*16 + l16) * NQK + h*64 + 8*quad;
  const bfv8 qA[2] = { *(const bfv8*)qAp, *(const bfv8*)(qAp + 32) };
  const bfv8 qB[2] = { *(const bfv8*)qBp, *(const bfv8*)(qBp + 32) };

  float psA = 0.f, psB = 0.f;
  f32x4 oA[4], oB[4];
  #pragma unroll
  for (int d = 0; d < 4; ++d) oA[d] = oB[d] = (f32x4){0.f, 0.f, 0.f, 0.f};

  const int srow = lane >> 3, slot = lane & 7;
  const u16* Kg = qkv + (size_t)(b*T_) * NQK + 1024 + kvh*64;
  const u16* Vg = vT  + (size_t)((b*HKV_ + kvh) * 64) * T_;

  auto stage = [&](int kt, int buf) {
    const int s0 = kt * 64;
    #pragma unroll
    for (int u = 0; u < 2; ++u) {
      const int base = wave*16 + u*8;
      const int r  = base + srow;
      const int kc = slot ^ (r & 7);           // XOR chunk swizzle
      load16(Kg + (size_t)(s0 + r) * NQK + kc*8, Kl[buf] + base*64);
      load16(Vg + (size_t)r * T_ + s0 + kc*8,    Vl[buf] + base*64);
    }
  };

  stage(0, 0);
  const int qColA = qtA*64 + wave*16 + l16;    // lane's q row (strip A)
  const int qColB = qtB*64 + wave*16 + l16;

  // Phase 1: kt in [0, qtA) — both strips, no diag
  for (int kt = 0; kt < qtA; ++kt) {
    __syncthreads();
    stage(kt + 1, (kt + 1) & 1);
    attn_tile<true, false, false>(Kl[kt & 1], Vl[kt & 1], l16, quad, qA, qB,
                                  psA, psB, oA, oB, qColA, qColB, kt*64);
  }
  // kt = qtA — both strips, diag on A (qtA < nk-1 always)
  {
    const int kt = qtA;
    __syncthreads();
    stage(kt + 1, (kt + 1) & 1);
    attn_tile<true, true, false>(Kl[kt & 1], Vl[kt & 1], l16, quad, qA, qB,
                                 psA, psB, oA, oB, qColA, qColB, kt*64);
  }
  // Phase 2: kt in (qtA, nk-1) — strip B only
  for (int kt = qtA + 1; kt < nk - 1; ++kt) {
    __syncthreads();
    stage(kt + 1, (kt + 1) & 1);
    attn_tile<false, false, false>(Kl[kt & 1], Vl[kt & 1], l16, quad, qA, qB,
                                   psA, psB, oA, oB, qColA, qColB, kt*64);
  }
  // kt = nk-1 — strip B, diag
  {
    const int kt = nk - 1;
    __syncthreads();
    attn_tile<false, false, true>(Kl[kt & 1], Vl[kt & 1], l16, quad, qA, qB,
                                  psA, psB, oA, oB, qColA, qColB, kt*64);
  }

  // row sums: partials live on the 4 quads of each q-row lane
  #pragma unroll
  for (int off = 16; off < 64; off <<= 1) {
    psA += __shfl_xor(psA, off);
    psB += __shfl_xor(psB, off);
  }
  const float ivA = 1.0f / psA, ivB = 1.0f / psB;

  // O^T C-layout: col=l16=qrow, row=4*quad+r = d (+16*dt) -> pack 4 d's per store
  #pragma unroll
  for (int dt = 0; dt < 4; ++dt) {
    ushort4 wA, wB;
    wA.x = f2bf(oA[dt][0]*ivA); wA.y = f2bf(oA[dt][1]*ivA);
    wA.z = f2bf(oA[dt][2]*ivA); wA.w = f2bf(oA[dt][3]*ivA);
    wB.x = f2bf(oB[dt][0]*ivB); wB.y = f2bf(oB[dt][1]*ivB);
    wB.z = f2bf(oB[dt][2]*ivB); wB.w = f2bf(oB[dt][3]*ivB);
    *(ushort4*)(o + (size_t)(b*T_ + qColA) * D_ + h*64 + dt*16 + 4*quad) = wA;
    *(ushort4*)(o + (size_t)(b*T_ + qColB) * D_ + h*64 + dt*16 + 4*quad) = wB;
  }
}

// ---------------- launch ----------------
extern "C" void kernel_launch(void* const* d_in, const int* in_sizes, int n_in,
                              void* d_out, int out_size, void* d_ws, size_t ws_size,
                              hipStream_t stream) {
  const float* x  = (const float*)d_in[0];
  const float* Wq = (const float*)d_in[1];
  const float* Wk = (const float*)d_in[2];
  const float* Wv = (const float*)d_in[3];
  const float* Wp = (const float*)d_in[4];
  const float* qg = (const float*)d_in[5];

  u16* xb   = (u16*)d_ws;                        // 4096 x 1024 (reused as ob)
  u16* wqkv = xb   + (size_t)BT_ * D_;           // 1536 x 1024
  u16* wpb  = wqkv + (size_t)1536 * D_;          // 1024 x 1024 (contiguous after wqkv)
  u16* qkvb = wpb  + (size_t)D_ * D_;            // 4096 x 1280 (Q|K)
  u16* vT   = qkvb + (size_t)BT_ * NQK;          // [2][4][64][2048]
  u16* ob   = xb;

  conv_all_kernel<<<dim3((4194304 + 2621440) / 1024), dim3(256), 0, stream>>>(
      x, Wq, Wk, Wv, Wp, xb);

  gemm_bt<2><<<dim3(12, 32), dim3(256), 0, stream>>>(xb, wqkv, qkvb, vT, qg, BT_, 1536, D_);
  attn_kernel<<<dim3(16, H_, B_), dim3(256), 0, stream>>>(qkvb, vT, ob);
  gemm_bt<0><<<dim3(8, 32), dim3(256), 0, stream>>>(ob, wpb, d_out, (u16*)nullptr, nullptr, BT_, D_, D_);
}

// Round 5
// 155.566 us; speedup vs baseline: 1.8973x; 1.0055x over previous
//
#include <hip/hip_runtime.h>

typedef unsigned short u16;
typedef unsigned int   u32;
typedef __bf16 bfv8 __attribute__((ext_vector_type(8)));   // MFMA A/B frag: 8 bf16
typedef float  f32x4 __attribute__((ext_vector_type(4)));  // MFMA C/D frag
typedef short  s16x4 __attribute__((ext_vector_type(4)));  // 16x16x16 bf16_1k frag

#define B_   2
#define T_   2048
#define D_   1024
#define H_   16
#define HKV_ 4
#define NQK  1280            // qkv buffer holds Q(1024) + K(256); V goes to vT
#define BT_  (B_*T_)
// q_gain fold also includes 1/sqrt(64)=0.125 and log2(e) (softmax in log2 domain)
#define QSCALE 0.18033688011112042f
#define L2_10K 0.41524101186092515f   // log2(10000)/32
#define I2PI   0.15915494309189535f   // 1/(2*pi) — HW trig input is revolutions

__device__ __forceinline__ u16 f2bf(float f) {   // native RNE cvt
  __bf16 h = (__bf16)f; u16 s; __builtin_memcpy(&s, &h, 2); return s;
}

// async global->LDS, 16B per lane; LDS dst = wave-uniform base + lane*16 (m104)
__device__ __forceinline__ void load16(const u16* g, u16* l) {
  auto gp = (const __attribute__((address_space(1))) u32*)(uintptr_t)g;
  auto lp = (__attribute__((address_space(3))) u32*)(uintptr_t)l;
  __builtin_amdgcn_global_load_lds(gp, lp, 16, 0, 0);
}

// HW trig: v_sin_f32/v_cos_f32 take revolutions; explicit fract reduction
__device__ __forceinline__ void hw_sincos_rev(float rev, float& s, float& c) {
  rev -= floorf(rev);                  // folds to v_fract_f32
  s = __builtin_amdgcn_sinf(rev);
  c = __builtin_amdgcn_cosf(rev);
}

// ---------------- fp32 -> bf16 convert: x AND all weights in ONE launch ----------
// dst is contiguous: xb(4194304) | Wq(1048576) | Wk(262144) | Wv(262144) | Wp(1048576)
__global__ void conv_all_kernel(const float* __restrict__ x,
                                const float* __restrict__ wq, const float* __restrict__ wk,
                                const float* __restrict__ wv, const float* __restrict__ wp,
                                u16* __restrict__ dst) {
  int i = (blockIdx.x * 256 + threadIdx.x) * 4;
  const float* s; int off;
  if (i < 4194304) { s = x; off = i; }
  else {
    int j = i - 4194304;
    if      (j < 1048576) { s = wq; off = j; }
    else if (j < 1310720) { s = wk; off = j - 1048576; }
    else if (j < 1572864) { s = wv; off = j - 1310720; }
    else                  { s = wp; off = j - 1572864; }
  }
  float4 v = *(const float4*)(s + off);
  ushort4 o; o.x = f2bf(v.x); o.y = f2bf(v.y); o.z = f2bf(v.z); o.w = f2bf(v.w);
  *(ushort4*)(dst + i) = o;
}

// ---------------- bf16 GEMM, C = A(M,K) @ B(N,K)^T ----------------
// R15: OCCUPANCY config. R4 post-mortem: R3's differential gives attn=36.6us,
// so GEMMs+gaps ~= 68us ~= 320 TF — exactly m102's 1-block/CU shape point
// (320 TF @ N=2048 vs 833 TF @ 4 blocks/CU, SAME kernel). All prior configs
// had identical 6 waves/CU — hence identical perf. Fix: tile 64Mx128N,
// 4 waves, each wave owns 32Mx64N (full 64-col strip preserved: the fused
// RoPE epilogue pairs cols j<->j+32 inside ONE wave's accs, so waves must
// own N=64). QKV: 12x64=768 blocks = 3/CU = 12 waves/CU (2x prior);
// proj: 8x64=512 = 2/CU = 8 waves/CU (2x). LDS 24KB/block (72KB @ 3 blocks).
// Schedule frozen (1 barrier/K-step, 2 LDS buffers, DMA prefetch 1 deep) +
// T1 XCD-chunked swizzle (R4: -1.1us; nwg=768/512 both %8==0, bijective).
// MODE 0: f32 out ld=N.  MODE 2: fused QKV epilogue (RoPE on Q/K, V->vT).
template<int MODE>
__global__ __launch_bounds__(256) void gemm_bt(const u16* __restrict__ A,
                                               const u16* __restrict__ Bm,
                                               void* __restrict__ C,
                                               u16* __restrict__ vT,
                                               const float* __restrict__ qg,
                                               int M, int N, int K) {
  __shared__ __align__(16) u16 As[2][64 * 32];    //  8 KB
  __shared__ __align__(16) u16 Bs[2][128 * 32];   // 16 KB
  const int tid  = threadIdx.x;
  const int wave = tid >> 6, lane = tid & 63;
  const int quad = lane >> 4, l16 = lane & 15;
  // T1 XCD swizzle (compile-time gx: QKV grid x=12, proj grid x=8)
  const int gx   = (MODE == 2) ? 12 : 8;
  const int nwg  = gx * 64;
  const int orig = blockIdx.x + gx * blockIdx.y;
  const int lid  = (orig & 7) * (nwg >> 3) + (orig >> 3);
  const int m0 = (lid / gx) * 64, n0 = (lid % gx) * 128;
  const int wm = (wave >> 1) * 32, wn = (wave & 1) * 64;
  const int lr = lane >> 2, lc = (lane & 3) * 8;   // 4 lanes per 32-half row

  f32x4 acc[2][4];
  for (int mi = 0; mi < 2; ++mi)
    for (int ni = 0; ni < 4; ++ni) acc[mi][ni] = (f32x4){0.f, 0.f, 0.f, 0.f};

  // 12 chunks (A:4 + B:8) over 4 waves -> 3 loads per wave per stage
  auto stage = [&](int kk, int buf) {
    {                                        // A: 4 chunks of 16 rows, c = wave
      const int c = wave;
      load16(A + (size_t)(m0 + c*16 + lr) * K + kk + lc, As[buf] + c * 512);
    }
    #pragma unroll
    for (int u = 0; u < 2; ++u) {            // B: 8 chunks of 16 rows
      const int c = u * 4 + wave;
      load16(Bm + (size_t)(n0 + c*16 + lr) * K + kk + lc, Bs[buf] + c * 512);
    }
  };

  const int nIter = K >> 5;                  // 32
  stage(0, 0);
  for (int it = 0; it < nIter; ++it) {
    __syncthreads();                         // implicit vmcnt(0): DMA(it) done;
                                             // also protects buf[(it+1)&1] from prev reads
    if (it + 1 < nIter) stage(((it + 1) << 5), (it + 1) & 1);   // overlaps compute(it)
    const u16* Ab = As[it & 1];
    const u16* Bb = Bs[it & 1];
    bfv8 af[2], bf_[4];
    #pragma unroll
    for (int i = 0; i < 2; ++i) af[i]  = *(const bfv8*)(Ab + (wm + i*16 + l16)*32 + 8*quad);
    #pragma unroll
    for (int i = 0; i < 4; ++i) bf_[i] = *(const bfv8*)(Bb + (wn + i*16 + l16)*32 + 8*quad);
    #pragma unroll
    for (int mi = 0; mi < 2; ++mi)
      #pragma unroll
      for (int ni = 0; ni < 4; ++ni)
        acc[mi][ni] = __builtin_amdgcn_mfma_f32_16x16x32_bf16(af[mi], bf_[ni], acc[mi][ni], 0, 0, 0);
  }

  // C/D layout: row = 4*quad + reg, col = l16 (+16*ni + n0 + wn)
  const int nc = n0 + wn;                    // wave's 64-wide column strip base
  if (MODE == 0) {
    #pragma unroll
    for (int mi = 0; mi < 2; ++mi)
      #pragma unroll
      for (int ni = 0; ni < 4; ++ni)
        #pragma unroll
        for (int r = 0; r < 4; ++r)
          ((float*)C)[(size_t)(m0 + wm + mi*16 + 4*quad + r) * N + nc + ni*16 + l16]
            = acc[mi][ni][r];
  } else {
    if (nc < NQK) {                          // Q or K head: apply RoPE here
      const bool isQ = nc < 1024;
      const float gain = isQ ? qg[nc >> 6] * QSCALE : 1.0f;
      // lane's head-internal cols: j0=l16 (ni 0/2 pair), j1=l16+16 (ni 1/3 pair)
      const float inv0 = exp2f(-(float)l16 * L2_10K) * I2PI;          // rev/step
      const float inv1 = exp2f(-(float)(l16 + 16) * L2_10K) * I2PI;
      #pragma unroll
      for (int mi = 0; mi < 2; ++mi) {
        const int rowg = m0 + wm + mi*16 + 4*quad;
        u16* dst = (u16*)C + (size_t)rowg * NQK + nc + l16;
        #pragma unroll
        for (int r = 0; r < 4; ++r) {
          const int t = (rowg + r) & (T_ - 1);
          float s0, c0, s1, c1;
          hw_sincos_rev((float)t * inv0, s0, c0);
          hw_sincos_rev((float)t * inv1, s1, c1);
          const float x1a = acc[mi][0][r], x2a = acc[mi][2][r];
          const float x1b = acc[mi][1][r], x2b = acc[mi][3][r];
          u16* drow = dst + (size_t)r * NQK;
          drow[0]  = f2bf((x1a*c0 - x2a*s0) * gain);
          drow[16] = f2bf((x1b*c1 - x2b*s1) * gain);
          drow[32] = f2bf((x1a*s0 + x2a*c0) * gain);
          drow[48] = f2bf((x1b*s1 + x2b*c1) * gain);
        }
      }
    } else {              // V head -> transposed vT[b][kvh][d][t]
      const int kvh = (nc - NQK) >> 6;
      #pragma unroll
      for (int mi = 0; mi < 2; ++mi)
        #pragma unroll
        for (int ni = 0; ni < 4; ++ni) {
          const int d = ni*16 + l16;
          const int rowg = m0 + wm + mi*16 + 4*quad;
          const int bb = rowg >> 11, t = rowg & (T_ - 1);
          ushort4 w4;
          w4.x = f2bf(acc[mi][ni][0]); w4.y = f2bf(acc[mi][ni][1]);
          w4.z = f2bf(acc[mi][ni][2]); w4.w = f2bf(acc[mi][ni][3]);
          *(ushort4*)(vT + ((size_t)((bb*HKV_ + kvh)*64 + d)) * T_ + t) = w4;
        }
    }
  }
}

// ---------------- Flash attention (causal, GQA, paired q-tiles, S^T trick) ----------------
// R8 version VERBATIM (36.6 us by R3 differential). R2 (counted-vmcnt, 4 buf):
// +4.5us — asm WAITBAR defeats compiler lgkmcnt scheduling. R3 (no LDS,
// direct global): +129us — latency-bound (MfmaUtil 5.9%), the 1-deep DMA
// prefetch was load-bearing. This structure is a verified local optimum.
// Paired q-tiles (i, 31-i): uniform 33 strip-tiles/block AND K/V frag reads
// shared across both strips. St = K Q^T (C-layout lane l16 = q-row, keys
// 4*quad+r) feeds P directly into PV (O^T = V^T P^T) as 16x16x16bf16_1k
// B-frags — no P LDS round-trip. Fixed-max softmax (M=0, log2 domain).
// COMPILE-TIME strip/diag specialization (R7 lesson: runtime bools get
// if-converted inside unrolled loops -> dead strip's exp2/MFMA chain executes).
template<bool DOA, bool DIAGA, bool DIAGB>
__device__ __forceinline__ void attn_tile(const u16* KB, const u16* VB,
                                          int l16, int quad,
                                          const bfv8* qA, const bfv8* qB,
                                          float& psA, float& psB,
                                          f32x4 oA[4], f32x4 oB[4],
                                          int qColA, int qColB, int s0) {
  const int sw = l16 & 7;
  f32x4 stA[4], stB[4];
  #pragma unroll
  for (int ni = 0; ni < 4; ++ni) {
    const int row = ni*16 + l16;           // key row in K tile
    bfv8 k0 = *(const bfv8*)(KB + row*64 + 8*(quad ^ sw));
    bfv8 k1 = *(const bfv8*)(KB + row*64 + 8*((quad + 4) ^ sw));
    if (DOA) {
      stA[ni] = __builtin_amdgcn_mfma_f32_16x16x32_bf16(k0, qA[0], (f32x4){0.f,0.f,0.f,0.f}, 0, 0, 0);
      stA[ni] = __builtin_amdgcn_mfma_f32_16x16x32_bf16(k1, qA[1], stA[ni], 0, 0, 0);
    }
    stB[ni] = __builtin_amdgcn_mfma_f32_16x16x32_bf16(k0, qB[0], (f32x4){0.f,0.f,0.f,0.f}, 0, 0, 0);
    stB[ni] = __builtin_amdgcn_mfma_f32_16x16x32_bf16(k1, qB[1], stB[ni], 0, 0, 0);
  }
  // mask + exp2 + per-lane row-sum + pack to bf16 B-frags (P^T in registers)
  s16x4 pbA[4], pbB[4];
  #pragma unroll
  for (int ni = 0; ni < 4; ++ni)
    #pragma unroll
    for (int r = 0; r < 4; ++r) {
      const int key = s0 + ni*16 + 4*quad + r;
      if (DOA) {
        float v = stA[ni][r];
        if (DIAGA) v = (key <= qColA) ? v : -3.0e38f;
        const float p = __builtin_amdgcn_exp2f(v);
        psA += p;
        pbA[ni][r] = (short)f2bf(p);
      }
      float v = stB[ni][r];
      if (DIAGB) v = (key <= qColB) ? v : -3.0e38f;
      const float p = __builtin_amdgcn_exp2f(v);
      psB += p;
      pbB[ni][r] = (short)f2bf(p);
    }
  // O^T += V^T P^T  (shared V frags)
  #pragma unroll
  for (int ni = 0; ni < 4; ++ni) {
    const int vofs = 8*((2*ni + (quad >> 1)) ^ sw) + 4*(quad & 1);
    #pragma unroll
    for (int dt = 0; dt < 4; ++dt) {
      s16x4 va = *(const s16x4*)(VB + (dt*16 + l16)*64 + vofs);
      if (DOA) oA[dt] = __builtin_amdgcn_mfma_f32_16x16x16bf16_1k(va, pbA[ni], oA[dt], 0, 0, 0);
      oB[dt] = __builtin_amdgcn_mfma_f32_16x16x16bf16_1k(va, pbB[ni], oB[dt], 0, 0, 0);
    }
  }
}

__global__ __launch_bounds__(256) void attn_kernel(const u16* __restrict__ qkv,
                                                   const u16* __restrict__ vT,
                                                   u16* __restrict__ o) {
  const int pr = blockIdx.x;            // pair id 0..15 -> q-tiles (pr, 31-pr)
  const int h  = blockIdx.y;
  const int b  = blockIdx.z;
  const int kvh = h >> 2;
  const int tid = threadIdx.x;
  const int wave = tid >> 6, lane = tid & 63;
  const int quad = lane >> 4, l16 = lane & 15;

  const int qtA = pr, qtB = 31 - pr;
  const int nk  = qtB + 1;              // qtA < qtB always (pr in 0..15)

  __shared__ __align__(16) u16 Kl[2][64 * 64];
  __shared__ __align__(16) u16 Vl[2][64 * 64];

  const u16* qAp = qkv + (size_t)(b*T_ + qtA*64 + wave*16 + l16) * NQK + h*64 + 8*quad;
  const u16* qBp = qkv + (size_t)(b*T_ + qtB*64 + wave*16 + l16) * NQK + h*64 + 8*quad;
  const bfv8 qA[2] = { *(const bfv8*)qAp, *(const bfv8*)(qAp + 32) };
  const bfv8 qB[2] = { *(const bfv8*)qBp, *(const bfv8*)(qBp + 32) };

  float psA = 0.f, psB = 0.f;
  f32x4 oA[4], oB[4];
  #pragma unroll
  for (int d = 0; d < 4; ++d) oA[d] = oB[d] = (f32x4){0.f, 0.f, 0.f, 0.f};

  const int srow = lane >> 3, slot = lane & 7;
  const u16* Kg = qkv + (size_t)(b*T_) * NQK + 1024 + kvh*64;
  const u16* Vg = vT  + (size_t)((b*HKV_ + kvh) * 64) * T_;

  auto stage = [&](int kt, int buf) {
    const int s0 = kt * 64;
    #pragma unroll
    for (int u = 0; u < 2; ++u) {
      const int base = wave*16 + u*8;
      const int r  = base + srow;
      const int kc = slot ^ (r & 7);           // XOR chunk swizzle
      load16(Kg + (size_t)(s0 + r) * NQK + kc*8, Kl[buf] + base*64);
      load16(Vg + (size_t)r * T_ + s0 + kc*8,    Vl[buf] + base*64);
    }
  };

  stage(0, 0);
  const int qColA = qtA*64 + wave*16 + l16;    // lane's q row (strip A)
  const int qColB = qtB*64 + wave*16 + l16;

  // Phase 1: kt in [0, qtA) — both strips, no diag
  for (int kt = 0; kt < qtA; ++kt) {
    __syncthreads();
    stage(kt + 1, (kt + 1) & 1);
    attn_tile<true, false, false>(Kl[kt & 1], Vl[kt & 1], l16, quad, qA, qB,
                                  psA, psB, oA, oB, qColA, qColB, kt*64);
  }
  // kt = qtA — both strips, diag on A (qtA < nk-1 always)
  {
    const int kt = qtA;
    __syncthreads();
    stage(kt + 1, (kt + 1) & 1);
    attn_tile<true, true, false>(Kl[kt & 1], Vl[kt & 1], l16, quad, qA, qB,
                                 psA, psB, oA, oB, qColA, qColB, kt*64);
  }
  // Phase 2: kt in (qtA, nk-1) — strip B only
  for (int kt = qtA + 1; kt < nk - 1; ++kt) {
    __syncthreads();
    stage(kt + 1, (kt + 1) & 1);
    attn_tile<false, false, false>(Kl[kt & 1], Vl[kt & 1], l16, quad, qA, qB,
                                   psA, psB, oA, oB, qColA, qColB, kt*64);
  }
  // kt = nk-1 — strip B, diag
  {
    const int kt = nk - 1;
    __syncthreads();
    attn_tile<false, false, true>(Kl[kt & 1], Vl[kt & 1], l16, quad, qA, qB,
                                  psA, psB, oA, oB, qColA, qColB, kt*64);
  }

  // row sums: partials live on the 4 quads of each q-row lane
  #pragma unroll
  for (int off = 16; off < 64; off <<= 1) {
    psA += __shfl_xor(psA, off);
    psB += __shfl_xor(psB, off);
  }
  const float ivA = 1.0f / psA, ivB = 1.0f / psB;

  // O^T C-layout: col=l16=qrow, row=4*quad+r = d (+16*dt) -> pack 4 d's per store
  #pragma unroll
  for (int dt = 0; dt < 4; ++dt) {
    ushort4 wA, wB;
    wA.x = f2bf(oA[dt][0]*ivA); wA.y = f2bf(oA[dt][1]*ivA);
    wA.z = f2bf(oA[dt][2]*ivA); wA.w = f2bf(oA[dt][3]*ivA);
    wB.x = f2bf(oB[dt][0]*ivB); wB.y = f2bf(oB[dt][1]*ivB);
    wB.z = f2bf(oB[dt][2]*ivB); wB.w = f2bf(oB[dt][3]*ivB);
    *(ushort4*)(o + (size_t)(b*T_ + qColA) * D_ + h*64 + dt*16 + 4*quad) = wA;
    *(ushort4*)(o + (size_t)(b*T_ + qColB) * D_ + h*64 + dt*16 + 4*quad) = wB;
  }
}

// ---------------- launch ----------------
extern "C" void kernel_launch(void* const* d_in, const int* in_sizes, int n_in,
                              void* d_out, int out_size, void* d_ws, size_t ws_size,
                              hipStream_t stream) {
  const float* x  = (const float*)d_in[0];
  const float* Wq = (const float*)d_in[1];
  const float* Wk = (const float*)d_in[2];
  const float* Wv = (const float*)d_in[3];
  const float* Wp = (const float*)d_in[4];
  const float* qg = (const float*)d_in[5];

  u16* xb   = (u16*)d_ws;                        // 4096 x 1024 (reused as ob)
  u16* wqkv = xb   + (size_t)BT_ * D_;           // 1536 x 1024
  u16* wpb  = wqkv + (size_t)1536 * D_;          // 1024 x 1024 (contiguous after wqkv)
  u16* qkvb = wpb  + (size_t)D_ * D_;            // 4096 x 1280 (Q|K)
  u16* vT   = qkvb + (size_t)BT_ * NQK;          // [2][4][64][2048]
  u16* ob   = xb;

  conv_all_kernel<<<dim3((4194304 + 2621440) / 1024), dim3(256), 0, stream>>>(
      x, Wq, Wk, Wv, Wp, xb);

  gemm_bt<2><<<dim3(12, 64), dim3(256), 0, stream>>>(xb, wqkv, qkvb, vT, qg, BT_, 1536, D_);
  attn_kernel<<<dim3(16, H_, B_), dim3(256), 0, stream>>>(qkvb, vT, ob);
  gemm_bt<0><<<dim3(8, 64), dim3(256), 0, stream>>>(ob, wpb, d_out, (u16*)nullptr, nullptr, BT_, D_, D_);
}